// Round 7
// baseline (294.393 us; speedup 1.0000x reference)
//
#include <hip/hip_runtime.h>

typedef float        f32x4  __attribute__((ext_vector_type(4)));
typedef __bf16       bf16x8 __attribute__((ext_vector_type(8)));
typedef unsigned int u32x4  __attribute__((ext_vector_type(4)));
typedef unsigned short u16;

#define MFMA16(a,b,c) __builtin_amdgcn_mfma_f32_16x16x32_bf16((a),(b),(c),0,0,0)

// ---- fp32 -> bf16 hi/lo split. hi = trunc, lo = RNE(x-hi) ----
__device__ __forceinline__ unsigned bf_rnd(float x) {
    unsigned u = __float_as_uint(x);
    return (u + 0x7FFFu + ((u >> 16) & 1u)) & 0xFFFF0000u;
}
__device__ __forceinline__ void split_bf(float x, unsigned &h, unsigned &l) {
    unsigned hr = bf_rnd(x);
    h = hr >> 16;
    float lo = x - __uint_as_float(hr);
    l = bf_rnd(lo) >> 16;
}
__device__ __forceinline__ void split8q(const f32x4 a, const f32x4 b, bf16x8 &hv, bf16x8 &lv) {
    u32x4 hp, lp;
    #pragma unroll
    for (int i = 0; i < 2; ++i) {
        float x0 = (i ? b : a)[0], x1 = (i ? b : a)[1], x2 = (i ? b : a)[2], x3 = (i ? b : a)[3];
        unsigned h0 = __float_as_uint(x0) & 0xFFFF0000u;
        unsigned h1 = __float_as_uint(x1) & 0xFFFF0000u;
        unsigned h2 = __float_as_uint(x2) & 0xFFFF0000u;
        unsigned h3 = __float_as_uint(x3) & 0xFFFF0000u;
        unsigned l0 = bf_rnd(x0 - __uint_as_float(h0));
        unsigned l1 = bf_rnd(x1 - __uint_as_float(h1));
        unsigned l2 = bf_rnd(x2 - __uint_as_float(h2));
        unsigned l3 = bf_rnd(x3 - __uint_as_float(h3));
        hp[i*2+0] = (h0 >> 16) | h1;  lp[i*2+0] = (l0 >> 16) | l1;
        hp[i*2+1] = (h2 >> 16) | h3;  lp[i*2+1] = (l2 >> 16) | l3;
    }
    hv = __builtin_bit_cast(bf16x8, hp);
    lv = __builtin_bit_cast(bf16x8, lp);
}
__device__ __forceinline__ bf16x8 ld16(const u16* p) {
    return __builtin_bit_cast(bf16x8, *(const u32x4*)p);
}

// =====================================================================
// K0: pre-split weights into FRAGMENT-CONTIGUOUS bf16 hi/lo layout:
// frag F holds a 16(rows)x32(k) MFMA B-operand tile; a wave's ld16 at
// F*512 + lane*8 u16 is a contiguous 1KB load.
//   We: F = (f>>4)*4 + (e>>5)        (32 frags)
//   Wr: F = (h>>4)*12 + (k>>5)       (192 frags)
//   W0/W1: F = (h>>4)*8 + (k>>5)     (128 frags)
// lane = ((k>>3)&3)*16 + (row&15), elem = k&7.
// =====================================================================
__global__ __launch_bounds__(256) void k_prep(
    const float* __restrict__ We, const float* __restrict__ Wr,
    const float* __restrict__ W0, const float* __restrict__ W1,
    u16* __restrict__ WeTh, u16* __restrict__ WeTl,
    u16* __restrict__ WrTh, u16* __restrict__ WrTl,
    u16* __restrict__ W0Th, u16* __restrict__ W0Tl,
    u16* __restrict__ W1Th, u16* __restrict__ W1Tl)
{
    int t = blockIdx.x * 256 + threadIdx.x;
    float v; u16 *dh, *dl; int dst;
    if (t < 16384) {
        int f = t & 127, e = t >> 7;
        v = We[e*128 + f];
        int F = (f>>4)*4 + (e>>5);
        dst = F*512 + (((e>>3)&3)*16 + (f&15))*8 + (e&7);
        dh = WeTh; dl = WeTl;
    } else if (t < 114688) {
        int u = t - 16384; int h = u & 255, k = u >> 8;
        v = Wr[k*256 + h];
        int F = (h>>4)*12 + (k>>5);
        dst = F*512 + (((k>>3)&3)*16 + (h&15))*8 + (k&7);
        dh = WrTh; dl = WrTl;
    } else if (t < 180224) {
        int u = t - 114688; int h = u & 255, k = u >> 8;
        v = W0[k*256 + h];
        int F = (h>>4)*8 + (k>>5);
        dst = F*512 + (((k>>3)&3)*16 + (h&15))*8 + (k&7);
        dh = W0Th; dl = W0Tl;
    } else {
        int u = t - 180224; int h = u & 255, k = u >> 8;
        v = W1[k*256 + h];
        int F = (h>>4)*8 + (k>>5);
        dst = F*512 + (((k>>3)&3)*16 + (h&15))*8 + (k&7);
        dh = W1Th; dl = W1Tl;
    }
    unsigned hh, ll; split_bf(v, hh, ll);
    dh[dst] = (u16)hh; dl[dst] = (u16)ll;
}

// =====================================================================
// K1: fused edge-mapper + msg_e partial reduction. Barrier-free, LDS-free,
// all-register, double-buffered E prefetch (statically named bufs).
// Grid 256 = 16b x 4jh(32 j) x 4c(32 i).  Block 512 thr = 8 waves:
// 2 j-groups(16) x 4 f-groups(32).  Per wave: W frags resident (64 VGPR),
// E slab 16 rows x 128 e direct global->reg (32+32 VGPR dbuf).
// amdgpu_waves_per_eu(2,2) pins the 256-VGPR tier (R2's spill fix).
// =====================================================================
__global__ __launch_bounds__(512) __attribute__((amdgpu_waves_per_eu(2, 2)))
void k_edge(
    const float* __restrict__ E, const float* __restrict__ A,
    const u16* __restrict__ WeTh, const u16* __restrict__ WeTl,
    const float* __restrict__ be, float* __restrict__ part)
{
    const int tid  = threadIdx.x;
    const int lane = tid & 63;
    const int wv   = tid >> 6;
    const int lrow = lane & 15;
    const int lk   = lane >> 4;
    const int jg   = wv >> 2;          // 0/1
    const int fg   = wv & 3;           // 0..3
    const int wm   = jg << 4;          // j-offset in block: 0/16
    const int wn   = fg << 5;          // f-offset: 0/32/64/96
    const int bid  = blockIdx.x;
    const int c    = bid & 3;
    const int jh   = (bid >> 2) & 3;
    const int b    = bid >> 4;
    const int i0   = c << 5;           // 32 i-slabs per block
    const int j0   = jh << 5;          // 32 j per block

    // ---- resident W fragments: fb = fg*2+n, F = fb*4+k  (64 VGPR) ----
    bf16x8 wh[2][4], wl[2][4];
    #pragma unroll
    for (int n = 0; n < 2; ++n)
        #pragma unroll
        for (int k = 0; k < 4; ++k) {
            const int off = (((fg*2 + n)*4) + k)*512 + lane*8;
            wh[n][k] = ld16(WeTh + off);
            wl[n][k] = ld16(WeTl + off);
        }
    float ber[2];
    #pragma unroll
    for (int n = 0; n < 2; ++n) ber[n] = be[wn + n*16 + lrow];

    // per-lane row pointer: row = j0 + wm + lrow, cols lk*8 + ...
    const float* Erow = E + ((size_t)(b*128 + i0)*128 + j0 + wm + lrow)*128 + lk*8;
    const float* Arow = A + ((size_t)(b*128 + i0))*128 + j0 + wm + lk*4;

#define LOADSLAB(dst, adst, s)                                          \
    {                                                                   \
        const float* p = Erow + (size_t)(s)*16384;                      \
        _Pragma("unroll")                                               \
        for (int k = 0; k < 4; ++k) {                                   \
            dst[k*2+0] = *(const f32x4*)(p + k*32);                     \
            dst[k*2+1] = *(const f32x4*)(p + k*32 + 4);                 \
        }                                                               \
        adst = *(const f32x4*)(Arow + (size_t)(s)*128);                 \
    }

    f32x4 ebA[8], ebB[8], a4A, a4B;
    LOADSLAB(ebA, a4A, 0)

    f32x4 P[2] = {};   // msg_e partials, live whole loop

#define STEP(EBC, AC, EBN, AN, s)                                       \
    {                                                                   \
        if ((s) < 31) LOADSLAB(EBN, AN, (s)+1)                          \
        f32x4 em0 = {}, em1 = {};                                       \
        _Pragma("unroll")                                               \
        for (int k = 0; k < 4; ++k) {                                   \
            bf16x8 eh, el; split8q(EBC[k*2], EBC[k*2+1], eh, el);       \
            em0 = MFMA16(eh, wh[0][k], em0);                            \
            em0 = MFMA16(eh, wl[0][k], em0);                            \
            em0 = MFMA16(el, wh[0][k], em0);                            \
            em1 = MFMA16(eh, wh[1][k], em1);                            \
            em1 = MFMA16(eh, wl[1][k], em1);                            \
            em1 = MFMA16(el, wh[1][k], em1);                            \
        }                                                               \
        _Pragma("unroll")                                               \
        for (int r = 0; r < 4; ++r) {                                   \
            float v0 = fmaxf(em0[r] + ber[0], 0.0f);                    \
            float v1 = fmaxf(em1[r] + ber[1], 0.0f);                    \
            P[0][r] += AC[r] * v0;                                      \
            P[1][r] += AC[r] * v1;                                      \
        }                                                               \
    }

    for (int s = 0; s < 32; s += 2) {
        STEP(ebA, a4A, ebB, a4B, s)
        STEP(ebB, a4B, ebA, a4A, s+1)
    }
#undef STEP
#undef LOADSLAB

    // partial tile: part[bid][32 j][128 f]
    float* op = part + (size_t)bid * 4096;
    #pragma unroll
    for (int r = 0; r < 4; ++r) {
        const int j = wm + lk*4 + r;
        #pragma unroll
        for (int n = 0; n < 2; ++n)
            op[j*128 + wn + n*16 + lrow] = P[n][r];
    }
}

// =====================================================================
// K2 (role-split, grid 512): blocks 0..255 reduce msg_e partials (4 chunks),
// blocks 256..511 compute msg_x = A^T X. Output msg pre-split bf16 hi/lo.
// =====================================================================
__global__ __launch_bounds__(256) void k_msg(
    const float* __restrict__ A, const float* __restrict__ X,
    const float* __restrict__ part,
    u16* __restrict__ msg_h, u16* __restrict__ msg_l)
{
    const int bid = blockIdx.x;
    const int tid = threadIdx.x;
    __shared__ float sAt[128*8];

    if (bid < 256) {
        const int b = bid >> 4, jt = bid & 15;
        #pragma unroll
        for (int q = 0; q < 4; ++q) {
            const int e   = (q << 8) + tid;
            const int row = jt*8 + (e >> 7);   // global j
            const int f   = e & 127;
            const float* p = part + ((size_t)(b*16 + (row >> 5)*4))*4096
                                  + (row & 31)*128 + f;
            float ssum = 0.f;
            #pragma unroll
            for (int cc = 0; cc < 4; ++cc) ssum += p[(size_t)cc*4096];
            unsigned hh, ll; split_bf(ssum, hh, ll);
            const size_t o = (size_t)(b*128 + row)*384 + 256 + f;
            msg_h[o] = (u16)hh; msg_l[o] = (u16)ll;
        }
    } else {
        const int idx = bid - 256;
        const int b = idx >> 4, jt = idx & 15, j0 = jt << 3;
        #pragma unroll
        for (int q = 0; q < 4; ++q) {
            const int e = tid + q*256;
            sAt[e] = A[(size_t)(b*128 + (e >> 3))*128 + j0 + (e & 7)];
        }
        __syncthreads();
        const int h = tid;
        float acc[8] = {};
        const float* Xb = X + (size_t)b*32768 + h;
        #pragma unroll 2
        for (int i = 0; i < 128; ++i) {
            const float x  = Xb[(size_t)i*256];
            const f32x4 a0 = *(const f32x4*)(sAt + i*8);
            const f32x4 a1 = *(const f32x4*)(sAt + i*8 + 4);
            acc[0] += a0[0]*x; acc[1] += a0[1]*x; acc[2] += a0[2]*x; acc[3] += a0[3]*x;
            acc[4] += a1[0]*x; acc[5] += a1[1]*x; acc[6] += a1[2]*x; acc[7] += a1[3]*x;
        }
        #pragma unroll
        for (int jj = 0; jj < 8; ++jj) {
            unsigned hh, ll; split_bf(acc[jj], hh, ll);
            const size_t o = (size_t)(b*128 + j0 + jj)*384 + h;
            msg_h[o] = (u16)hh; msg_l[o] = (u16)ll;
        }
    }
}

// =====================================================================
// K3/K4/K5: tail GEMM, pure-register MFMA. B in fragment-contiguous layout.
// out(2048x256) = [ (1+eps)*res + ] relu(In(2048xKT) @ W(KTx256) + bias)
// =====================================================================
template<int KT, bool RES, bool F32OUT>
__global__ __launch_bounds__(256) void k_tail(
    const u16* __restrict__ Ah, const u16* __restrict__ Al,
    const u16* __restrict__ Bh, const u16* __restrict__ Bl,
    const float* __restrict__ bias, const float* __restrict__ res,
    const float* __restrict__ epsp,
    float* __restrict__ outf, u16* __restrict__ oh, u16* __restrict__ ol)
{
    constexpr int NB = KT/32;
    const int tid  = threadIdx.x;
    const int lane = tid & 63;
    const int wid  = tid >> 6;
    const int lrow = lane & 15;
    const int lk   = lane >> 4;
    const int wm   = (wid >> 1) << 4;
    const int wn   = (wid & 1)  << 5;
    const int r0   = blockIdx.x << 5;
    const int h0   = blockIdx.y << 6;

    const int arow = r0 + wm + lrow;
    const u16* pah = Ah + (size_t)arow*KT + lk*8;
    const u16* pal = Al + (size_t)arow*KT + lk*8;
    const size_t bb = (size_t)((h0 + wn) >> 4) * NB * 512 + lane*8;
    const u16* pbh = Bh + bb;
    const u16* pbl = Bl + bb;

    f32x4 P[2] = {};
    #pragma unroll
    for (int ks = 0; ks < NB; ++ks) {
        const bf16x8 ah  = ld16(pah + ks*32);
        const bf16x8 al  = ld16(pal + ks*32);
        const bf16x8 b0h = ld16(pbh + ks*512), b0l = ld16(pbl + ks*512);
        const bf16x8 b1h = ld16(pbh + (NB + ks)*512), b1l = ld16(pbl + (NB + ks)*512);
        P[0] = MFMA16(ah, b0h, P[0]);
        P[0] = MFMA16(ah, b0l, P[0]);
        P[0] = MFMA16(al, b0h, P[0]);
        P[1] = MFMA16(ah, b1h, P[1]);
        P[1] = MFMA16(ah, b1l, P[1]);
        P[1] = MFMA16(al, b1h, P[1]);
    }

    const float eps = RES ? epsp[0] : 0.f;
    #pragma unroll
    for (int n = 0; n < 2; ++n) {
        const int col = h0 + wn + n*16 + lrow;
        const float bv = bias[col];
        #pragma unroll
        for (int e = 0; e < 4; ++e) {
            const int r = r0 + wm + lk*4 + e;
            float v = fmaxf(P[n][e] + bv, 0.f);
            if (RES) v += (1.f + eps) * res[(size_t)r*256 + col];
            if (F32OUT) {
                outf[(size_t)r*256 + col] = v;
            } else {
                unsigned hh, ll; split_bf(v, hh, ll);
                oh[(size_t)r*256 + col] = (u16)hh;
                ol[(size_t)r*256 + col] = (u16)ll;
            }
        }
    }
}

extern "C" void kernel_launch(void* const* d_in, const int* in_sizes, int n_in,
                              void* d_out, int out_size, void* d_ws, size_t ws_size,
                              hipStream_t stream)
{
    const float* X   = (const float*)d_in[0];
    const float* E   = (const float*)d_in[1];
    const float* A   = (const float*)d_in[2];
    const float* eps = (const float*)d_in[3];
    const float* We  = (const float*)d_in[4];
    const float* be  = (const float*)d_in[5];
    const float* Wr  = (const float*)d_in[6];
    const float* br  = (const float*)d_in[7];
    const float* W0  = (const float*)d_in[8];
    const float* b0  = (const float*)d_in[9];
    const float* W1  = (const float*)d_in[10];
    const float* b1  = (const float*)d_in[11];
    float* out = (float*)d_out;

    u16* w = (u16*)d_ws;
    u16* WeTh = w;              u16* WeTl = WeTh + 16384;
    u16* WrTh = WeTl + 16384;   u16* WrTl = WrTh + 98304;
    u16* W0Th = WrTl + 98304;   u16* W0Tl = W0Th + 65536;
    u16* W1Th = W0Tl + 65536;   u16* W1Tl = W1Th + 65536;
    u16* msg_h = W1Tl + 65536;  u16* msg_l = msg_h + 786432;
    u16* o1h = msg_l + 786432;  u16* o1l = o1h + 524288;
    u16* o2h = o1l + 524288;    u16* o2l = o2h + 524288;
    float* part = (float*)(o2l + 524288);   // 256 * 4096 f32 = 4 MB

    k_prep<<<960, 256, 0, stream>>>(We, Wr, W0, W1,
        WeTh, WeTl, WrTh, WrTl, W0Th, W0Tl, W1Th, W1Tl);
    k_edge<<<256, 512, 0, stream>>>(E, A, WeTh, WeTl, be, part);
    k_msg<<<512, 256, 0, stream>>>(A, X, part, msg_h, msg_l);
    k_tail<384, true , false><<<dim3(64,4), 256, 0, stream>>>(
        msg_h, msg_l, WrTh, WrTl, br, X, eps, nullptr, o1h, o1l);
    k_tail<256, false, false><<<dim3(64,4), 256, 0, stream>>>(
        o1h, o1l, W0Th, W0Tl, b0, nullptr, nullptr, nullptr, o2h, o2l);
    k_tail<256, false, true ><<<dim3(64,4), 256, 0, stream>>>(
        o2h, o2l, W1Th, W1Tl, b1, nullptr, nullptr, out, nullptr, nullptr);
}